// Round 1
// baseline (1038.785 us; speedup 1.0000x reference)
//
#include <hip/hip_runtime.h>
#include <math.h>

#define NN 20000
#define EE 100000
#define RR 4
#define HH 4
#define DD 64
#define FF 128
#define LL 2

// ---------------------------------------------------------------------------
// Encoder: x[n][d] = feat[n]@Wf + bf + bet[n]*Wc[0] + clo[n]*Wc[1] + bc
// block = 256 threads = 4 nodes x 64 lanes
__global__ __launch_bounds__(256) void encoder_kernel(
    const float* __restrict__ feat, const float* __restrict__ bet,
    const float* __restrict__ clo, const float* __restrict__ Wf,
    const float* __restrict__ bf, const float* __restrict__ Wc,
    const float* __restrict__ bc, float* __restrict__ x) {
  __shared__ float fs[4][FF];
  const int t = threadIdx.x;
  const int n0 = blockIdx.x * 4;
  for (int idx = t; idx < 4 * FF; idx += 256) {
    const int rr = idx >> 7, cc = idx & 127;
    const int n = n0 + rr;
    fs[rr][cc] = (n < NN) ? feat[(size_t)n * FF + cc] : 0.f;
  }
  __syncthreads();
  const int g = t >> 6, d = t & 63;
  const int n = n0 + g;
  if (n >= NN) return;
  float acc = bf[d] + bc[d] + bet[n] * Wc[d] + clo[n] * Wc[DD + d];
#pragma unroll 8
  for (int f = 0; f < FF; ++f) acc = fmaf(fs[g][f], Wf[f * DD + d], acc);
  x[(size_t)n * DD + d] = acc;
}

// ---------------------------------------------------------------------------
// CSR build
__global__ __launch_bounds__(256) void hist_kernel(
    const int* __restrict__ esrc, int* __restrict__ counts) {
  const int e = blockIdx.x * 256 + threadIdx.x;
  const int r = blockIdx.y;
  if (e < EE) atomicAdd(&counts[r * NN + esrc[(size_t)r * EE + e]], 1);
}

// one block per relation; exclusive scan of counts -> offs
__global__ __launch_bounds__(256) void scan_kernel(
    const int* __restrict__ counts, int* __restrict__ offs) {
  __shared__ int tmp[256];
  __shared__ int running;
  const int r = blockIdx.x;
  const int t = threadIdx.x;
  if (t == 0) {
    running = 0;
    offs[r * (NN + 1)] = 0;
  }
  __syncthreads();
  for (int base = 0; base < NN; base += 256) {
    const int i = base + t;
    int v = (i < NN) ? counts[r * NN + i] : 0;
    tmp[t] = v;
    __syncthreads();
#pragma unroll
    for (int sft = 1; sft < 256; sft <<= 1) {
      const int add = (t >= sft) ? tmp[t - sft] : 0;
      __syncthreads();
      tmp[t] += add;
      __syncthreads();
    }
    if (i < NN) offs[r * (NN + 1) + i + 1] = tmp[t] + running;
    __syncthreads();
    if (t == 255) running += tmp[255];
    __syncthreads();
  }
}

__global__ __launch_bounds__(256) void fill_kernel(
    const int* __restrict__ esrc, const int* __restrict__ etgt,
    const int* __restrict__ offs, int* __restrict__ cursor,
    int* __restrict__ csr) {
  const int e = blockIdx.x * 256 + threadIdx.x;
  const int r = blockIdx.y;
  if (e < EE) {
    const int s = esrc[(size_t)r * EE + e];
    const int pos = offs[r * (NN + 1) + s] + atomicAdd(&cursor[r * NN + s], 1);
    csr[(size_t)r * EE + pos] = etgt[(size_t)r * EE + e];
  }
}

// ---------------------------------------------------------------------------
// C[M x Nc] = A[M x 64] @ W[64 x Nc] + bias   (fp32, tile 64x64, 4x4 micro)
__global__ __launch_bounds__(256) void gemm64_kernel(
    const float* __restrict__ A, const float* __restrict__ W,
    const float* __restrict__ bias, float* __restrict__ C, int M, int Nc) {
  __shared__ float As[64][68];  // [k][m], padded: stride 272B (16B-mult)
  __shared__ float Ws[64][68];  // [k][n]
  const int t = threadIdx.x;
  const int m0 = blockIdx.x * 64;
  const int n0 = blockIdx.y * 64;
  {
    const int k4 = (t & 15) * 4;
    int rr = t >> 4;
#pragma unroll
    for (int p = 0; p < 4; ++p, rr += 16) {
      const int m = m0 + rr;
      float4 a = (m < M) ? *(const float4*)(A + (size_t)m * 64 + k4)
                         : make_float4(0.f, 0.f, 0.f, 0.f);
      As[k4 + 0][rr] = a.x;
      As[k4 + 1][rr] = a.y;
      As[k4 + 2][rr] = a.z;
      As[k4 + 3][rr] = a.w;
    }
  }
  {
    const int n4 = (t & 15) * 4;
    int kk = t >> 4;
#pragma unroll
    for (int p = 0; p < 4; ++p, kk += 16) {
      *(float4*)&Ws[kk][n4] = *(const float4*)(W + (size_t)kk * Nc + n0 + n4);
    }
  }
  __syncthreads();
  const int tm = (t >> 4) * 4;
  const int tn = (t & 15) * 4;
  float acc[4][4] = {};
#pragma unroll 8
  for (int kk = 0; kk < 64; ++kk) {
    const float4 a4 = *(const float4*)&As[kk][tm];
    const float4 w4 = *(const float4*)&Ws[kk][tn];
    const float av[4] = {a4.x, a4.y, a4.z, a4.w};
    const float wv[4] = {w4.x, w4.y, w4.z, w4.w};
#pragma unroll
    for (int i = 0; i < 4; ++i)
#pragma unroll
      for (int j = 0; j < 4; ++j) acc[i][j] = fmaf(av[i], wv[j], acc[i][j]);
  }
  const float4 b4 = *(const float4*)(bias + n0 + tn);
#pragma unroll
  for (int i = 0; i < 4; ++i) {
    const int m = m0 + tm + i;
    if (m < M) {
      float4 o;
      o.x = acc[i][0] + b4.x;
      o.y = acc[i][1] + b4.y;
      o.z = acc[i][2] + b4.z;
      o.w = acc[i][3] + b4.w;
      *(float4*)(C + (size_t)m * Nc + n0 + tn) = o;
    }
  }
}

// ---------------------------------------------------------------------------
// Per-node online-softmax attention for one (layer, relation).
// block = 256 threads = 4 heads (waves) x 64 lanes (d); one block per node.
__global__ __launch_bounds__(256) void attn_kernel(
    const float* __restrict__ q, const float* __restrict__ k,
    const float* __restrict__ v, const int* __restrict__ offs,
    const int* __restrict__ csr, const float* __restrict__ nsi,
    const float* __restrict__ sw_lr,  // &sign_w[l][0][r], stride over h = RR
    float* __restrict__ att_r) {
  const int n = blockIdx.x;
  const int t = threadIdx.x;
  const int h = t >> 6, d = t & 63;
  const int start = offs[n], end = offs[n + 1];
  const float qv = q[(size_t)n * 256 + h * 64 + d];
  const float c = 0.125f * nsi[n] * sw_lr[h * RR];
  float m = -INFINITY, den = 0.f, o = 0.f;
  for (int i = start; i < end; ++i) {
    const int tg = csr[i];
    const float kv = k[(size_t)tg * 256 + h * 64 + d];
    const float vv = v[(size_t)tg * 256 + h * 64 + d];
    float dot = qv * kv;
#pragma unroll
    for (int off = 32; off; off >>= 1) dot += __shfl_xor(dot, off);
    const float s = dot * c;
    const float mn = fmaxf(m, s);
    const float esc = __expf(m - mn);
    const float ew = __expf(s - mn);
    den = den * esc + ew;
    o = o * esc + ew * vv;
    m = mn;
  }
  att_r[(size_t)n * 256 + h * 64 + d] = o / (den + 1e-10f);
}

// ---------------------------------------------------------------------------
// acc_out[N x 64] += att_r[N x 256] @ Wp_slice[256 x 64]
// block = 256 threads: 16 nodes, each thread owns (node-group, col)
__global__ __launch_bounds__(256) void proj_accum_kernel(
    const float* __restrict__ att_r, const float* __restrict__ Wp,
    float* __restrict__ acc_out) {
  __shared__ float As[16][132];
  const int t = threadIdx.x;
  const int j = t & 63;
  const int mg = t >> 6;
  const int m0 = blockIdx.x * 16;
  float acc[4] = {0.f, 0.f, 0.f, 0.f};
  for (int kc = 0; kc < 256; kc += 128) {
    __syncthreads();
    {
      const int rr = t >> 4;
      const int k4 = (t & 15) * 4;
      const float* arow = att_r + (size_t)(m0 + rr) * 256 + kc;
      *(float4*)&As[rr][k4] = *(const float4*)(arow + k4);
      *(float4*)&As[rr][64 + k4] = *(const float4*)(arow + 64 + k4);
    }
    __syncthreads();
#pragma unroll 8
    for (int k = 0; k < 128; k += 4) {
      const float w0 = Wp[(size_t)(kc + k + 0) * 64 + j];
      const float w1 = Wp[(size_t)(kc + k + 1) * 64 + j];
      const float w2 = Wp[(size_t)(kc + k + 2) * 64 + j];
      const float w3 = Wp[(size_t)(kc + k + 3) * 64 + j];
#pragma unroll
      for (int i = 0; i < 4; ++i) {
        const float4 a4 = *(const float4*)&As[mg * 4 + i][k];
        float s = acc[i];
        s = fmaf(a4.x, w0, s);
        s = fmaf(a4.y, w1, s);
        s = fmaf(a4.z, w2, s);
        s = fmaf(a4.w, w3, s);
        acc[i] = s;
      }
    }
  }
#pragma unroll
  for (int i = 0; i < 4; ++i) {
    const int m = m0 + mg * 4 + i;
    acc_out[(size_t)m * 64 + j] += acc[i];
  }
}

// ---------------------------------------------------------------------------
// y = x + acc + bp ; LayerNorm(y) -> xout.  4 nodes/block, wave = one row.
__global__ __launch_bounds__(256) void addln_kernel(
    const float* __restrict__ x, const float* __restrict__ acc,
    const float* __restrict__ bp, const float* __restrict__ g,
    const float* __restrict__ b, float* __restrict__ xout) {
  const int t = threadIdx.x;
  const int n = blockIdx.x * 4 + (t >> 6);
  const int j = t & 63;
  const float y = x[(size_t)n * 64 + j] + acc[(size_t)n * 64 + j] + bp[j];
  float s = y, s2 = y * y;
#pragma unroll
  for (int off = 32; off; off >>= 1) {
    s += __shfl_xor(s, off);
    s2 += __shfl_xor(s2, off);
  }
  const float mu = s * (1.f / 64.f);
  const float var = s2 * (1.f / 64.f) - mu * mu;
  const float xo = (y - mu) * rsqrtf(var + 1e-5f) * g[j] + b[j];
  xout[(size_t)n * 64 + j] = xo;
}

// ---------------------------------------------------------------------------
extern "C" void kernel_launch(void* const* d_in, const int* in_sizes, int n_in,
                              void* d_out, int out_size, void* d_ws,
                              size_t ws_size, hipStream_t stream) {
  const float* feat = (const float*)d_in[1];
  const float* bet = (const float*)d_in[2];
  const float* clo = (const float*)d_in[3];
  const float* nsi = (const float*)d_in[4];
  const int* esrc = (const int*)d_in[5];
  const int* etgt = (const int*)d_in[6];
  const float* Wf = (const float*)d_in[7];
  const float* bf = (const float*)d_in[8];
  const float* Wc = (const float*)d_in[9];
  const float* bc = (const float*)d_in[10];
  const float* Wq = (const float*)d_in[11];
  const float* bq = (const float*)d_in[12];
  const float* Wk = (const float*)d_in[13];
  const float* bk = (const float*)d_in[14];
  const float* Wv = (const float*)d_in[15];
  const float* bv = (const float*)d_in[16];
  const float* Wp = (const float*)d_in[17];
  const float* bp = (const float*)d_in[18];
  const float* sw = (const float*)d_in[19];
  const float* lng = (const float*)d_in[20];
  const float* lnb = (const float*)d_in[21];
  float* out = (float*)d_out;

  // workspace bump allocator (256B aligned)
  char* base = (char*)d_ws;
  size_t off = 0;
  auto alloc = [&](size_t bytes) {
    void* p = base + off;
    off += (bytes + 255) & ~(size_t)255;
    return p;
  };
  float* xa = (float*)alloc((size_t)NN * DD * 4);        // 5.12 MB
  float* xb = (float*)alloc((size_t)NN * DD * 4);        // 5.12 MB
  float* qb = (float*)alloc((size_t)NN * HH * DD * 4);   // 20.48 MB
  float* kb = (float*)alloc((size_t)NN * HH * DD * 4);   // 20.48 MB
  float* vb = (float*)alloc((size_t)NN * HH * DD * 4);   // 20.48 MB
  float* attr = (float*)alloc((size_t)NN * HH * DD * 4); // 20.48 MB
  float* pacc = (float*)alloc((size_t)NN * DD * 4);      // 5.12 MB
  int* counts = (int*)alloc((size_t)RR * NN * 4);        // 0.32 MB
  int* offs = (int*)alloc((size_t)RR * (NN + 1) * 4);    // 0.32 MB
  int* csr = (int*)alloc((size_t)RR * EE * 4);           // 1.6 MB
  (void)ws_size;

  // ---- CSR build (edges shared across layers) ----
  hipMemsetAsync(counts, 0, (size_t)RR * NN * 4, stream);
  {
    dim3 g((EE + 255) / 256, RR);
    hipLaunchKernelGGL(hist_kernel, g, dim3(256), 0, stream, esrc, counts);
  }
  hipLaunchKernelGGL(scan_kernel, dim3(RR), dim3(256), 0, stream, counts, offs);
  hipMemsetAsync(counts, 0, (size_t)RR * NN * 4, stream);  // reuse as cursor
  {
    dim3 g((EE + 255) / 256, RR);
    hipLaunchKernelGGL(fill_kernel, g, dim3(256), 0, stream, esrc, etgt, offs,
                       counts, csr);
  }

  // ---- encoder ----
  hipLaunchKernelGGL(encoder_kernel, dim3((NN + 3) / 4), dim3(256), 0, stream,
                     feat, bet, clo, Wf, bf, Wc, bc, xa);

  const int gm = (NN + 63) / 64;  // 313
  for (int l = 0; l < LL; ++l) {
    const float* xin = (l == 0) ? xa : xb;
    float* xout = (l == LL - 1) ? out : xb;
    hipMemsetAsync(pacc, 0, (size_t)NN * DD * 4, stream);
    for (int r = 0; r < RR; ++r) {
      const size_t woff = (size_t)(l * RR + r) * DD * (HH * DD);
      const size_t boff = (size_t)(l * RR + r) * (HH * DD);
      hipLaunchKernelGGL(gemm64_kernel, dim3(gm, 4), dim3(256), 0, stream, xin,
                         Wq + woff, bq + boff, qb, NN, HH * DD);
      hipLaunchKernelGGL(gemm64_kernel, dim3(gm, 4), dim3(256), 0, stream, xin,
                         Wk + woff, bk + boff, kb, NN, HH * DD);
      hipLaunchKernelGGL(gemm64_kernel, dim3(gm, 4), dim3(256), 0, stream, xin,
                         Wv + woff, bv + boff, vb, NN, HH * DD);
      hipLaunchKernelGGL(attn_kernel, dim3(NN), dim3(256), 0, stream, qb, kb,
                         vb, offs + r * (NN + 1), csr + (size_t)r * EE, nsi,
                         sw + l * HH * RR + r, attr);
      hipLaunchKernelGGL(proj_accum_kernel, dim3(NN / 16), dim3(256), 0, stream,
                         attr, Wp + ((size_t)l * 1024 + r * 256) * 64, pacc);
    }
    hipLaunchKernelGGL(addln_kernel, dim3(NN / 4), dim3(256), 0, stream, xin,
                       pacc, bp + l * 64, lng + l * 64, lnb + l * 64, xout);
  }
}

// Round 2
// 559.867 us; speedup vs baseline: 1.8554x; 1.8554x over previous
//
#include <hip/hip_runtime.h>
#include <math.h>

#define NN 20000
#define EE 100000
#define RR 4
#define HH 4
#define DD 64
#define FF 128
#define LL 2
#define NB 79  // scan blocks per relation: ceil(20000/256)

typedef __attribute__((ext_vector_type(8))) short bf16x8;
typedef __attribute__((ext_vector_type(4))) float f32x4;

__device__ __forceinline__ ushort f2bf(float f) {
  uint u = __float_as_uint(f);
  u += 0x7FFFu + ((u >> 16) & 1u);
  return (ushort)(u >> 16);
}
__device__ __forceinline__ float bf2f(ushort h) {
  return __uint_as_float((uint)h << 16);
}

// ---------------------------------------------------------------------------
// Encoder: x = feat@Wf + bf + cen@Wc + bc ; writes fp32 x and bf16 xbf
__global__ __launch_bounds__(256) void encoder_kernel(
    const float* __restrict__ feat, const float* __restrict__ bet,
    const float* __restrict__ clo, const float* __restrict__ Wf,
    const float* __restrict__ bf, const float* __restrict__ Wc,
    const float* __restrict__ bc, float* __restrict__ x,
    ushort* __restrict__ xbf) {
  __shared__ float fs[4][FF];
  const int t = threadIdx.x;
  const int n0 = blockIdx.x * 4;
  for (int idx = t; idx < 4 * FF; idx += 256) {
    const int rr = idx >> 7, cc = idx & 127;
    const int n = n0 + rr;
    fs[rr][cc] = (n < NN) ? feat[(size_t)n * FF + cc] : 0.f;
  }
  __syncthreads();
  const int g = t >> 6, d = t & 63;
  const int n = n0 + g;
  if (n >= NN) return;
  float acc = bf[d] + bc[d] + bet[n] * Wc[d] + clo[n] * Wc[DD + d];
#pragma unroll 8
  for (int f = 0; f < FF; ++f) acc = fmaf(fs[g][f], Wf[f * DD + d], acc);
  x[(size_t)n * DD + d] = acc;
  xbf[(size_t)n * DD + d] = f2bf(acc);
}

// ---------------------------------------------------------------------------
// Weight pre-pack: wqkvT [l][r][768][64] bf16 (B^T), bqkv [l][r][768] f32,
//                  wpT [l][64][1024] bf16 (B^T)
__global__ __launch_bounds__(256) void pack_kernel(
    const float* __restrict__ Wq, const float* __restrict__ bq,
    const float* __restrict__ Wk, const float* __restrict__ bk,
    const float* __restrict__ Wv, const float* __restrict__ bv,
    const float* __restrict__ Wp, ushort* __restrict__ wqkvT,
    float* __restrict__ bqkv, ushort* __restrict__ wpT) {
  const int idx = blockIdx.x * 256 + threadIdx.x;
  const int P1 = LL * RR * 768 * 64;  // 393216
  if (idx < P1) {
    const int lr = idx / 49152;
    const int rem = idx % 49152;
    const int n = rem >> 6, k = rem & 63;
    const int sel = n >> 8, col = n & 255;
    const float* W = (sel == 0) ? Wq : (sel == 1) ? Wk : Wv;
    wqkvT[(size_t)lr * 49152 + n * 64 + k] =
        f2bf(W[(size_t)lr * 64 * 256 + k * 256 + col]);
    if (k == 0) {
      const float* B = (sel == 0) ? bq : (sel == 1) ? bk : bv;
      bqkv[lr * 768 + n] = B[lr * 256 + col];
    }
  } else if (idx < P1 + LL * 64 * 1024) {
    const int idx2 = idx - P1;
    const int l = idx2 >> 16;
    const int rem = idx2 & 65535;
    const int n = rem & 63, k = rem >> 6;
    wpT[(size_t)l * 65536 + n * 1024 + k] =
        f2bf(Wp[(size_t)l * 65536 + k * 64 + n]);
  }
}

// ---------------------------------------------------------------------------
// CSR build
__global__ __launch_bounds__(256) void hist_kernel(
    const int* __restrict__ esrc, int* __restrict__ counts) {
  const int e = blockIdx.x * 256 + threadIdx.x;
  const int r = blockIdx.y;
  if (e < EE) atomicAdd(&counts[r * NN + esrc[(size_t)r * EE + e]], 1);
}

// block-local inclusive scan; writes partial to offs[.. i+1], block sums to bsum
__global__ __launch_bounds__(256) void scanA_kernel(
    const int* __restrict__ counts, int* __restrict__ offs,
    int* __restrict__ bsum) {
  __shared__ int tmp[256];
  const int r = blockIdx.y, bx = blockIdx.x, t = threadIdx.x;
  const int i = bx * 256 + t;
  tmp[t] = (i < NN) ? counts[r * NN + i] : 0;
  __syncthreads();
#pragma unroll
  for (int s = 1; s < 256; s <<= 1) {
    const int add = (t >= s) ? tmp[t - s] : 0;
    __syncthreads();
    tmp[t] += add;
    __syncthreads();
  }
  if (i < NN) offs[r * (NN + 1) + i + 1] = tmp[t];
  if (t == 255) bsum[r * NB + bx] = tmp[255];
}

// scan the NB block sums per relation -> exclusive bases (in place)
__global__ __launch_bounds__(128) void scanB_kernel(int* __restrict__ bsum) {
  __shared__ int tmp[128];
  const int r = blockIdx.x, t = threadIdx.x;
  tmp[t] = (t < NB) ? bsum[r * NB + t] : 0;
  __syncthreads();
#pragma unroll
  for (int s = 1; s < 128; s <<= 1) {
    const int add = (t >= s) ? tmp[t - s] : 0;
    __syncthreads();
    tmp[t] += add;
    __syncthreads();
  }
  if (t < NB) bsum[r * NB + t] = (t == 0) ? 0 : tmp[t - 1];
}

__global__ __launch_bounds__(256) void scanC_kernel(
    const int* __restrict__ bsum, int* __restrict__ offs) {
  const int r = blockIdx.y, bx = blockIdx.x, t = threadIdx.x;
  const int i = bx * 256 + t;
  if (i < NN) offs[r * (NN + 1) + i + 1] += bsum[r * NB + bx];
  if (i == 0) offs[r * (NN + 1)] = 0;
}

__global__ __launch_bounds__(256) void fill_kernel(
    const int* __restrict__ esrc, const int* __restrict__ etgt,
    const int* __restrict__ offs, int* __restrict__ cursor,
    int* __restrict__ csr) {
  const int e = blockIdx.x * 256 + threadIdx.x;
  const int r = blockIdx.y;
  if (e < EE) {
    const int s = esrc[(size_t)r * EE + e];
    const int pos = offs[r * (NN + 1) + s] + atomicAdd(&cursor[r * NN + s], 1);
    csr[(size_t)r * EE + pos] = etgt[(size_t)r * EE + e];
  }
}

// ---------------------------------------------------------------------------
// Fused Q|K|V GEMM: qkv[n][768] = xbf[n][64] @ wT^T + bias, bf16 out.
// grid (ceil(N/64), 12), block 256 = 4 waves; wave w: rows m0+w*16..+15.
__global__ __launch_bounds__(256) void qkv_gemm_kernel(
    const ushort* __restrict__ xbf, const ushort* __restrict__ wT,
    const float* __restrict__ bias, ushort* __restrict__ qkv) {
  const int t = threadIdx.x;
  const int w = t >> 6, l = t & 63;
  const int hi = l >> 4, lo = l & 15;
  const int m0 = blockIdx.x * 64;
  const int n0 = blockIdx.y * 64;
  const int row = min(m0 + w * 16 + lo, NN - 1);
  const ushort* arow = xbf + (size_t)row * 64 + hi * 8;
  const bf16x8 a0 = *(const bf16x8*)(arow);
  const bf16x8 a1 = *(const bf16x8*)(arow + 32);
  f32x4 acc[4];
#pragma unroll
  for (int nt = 0; nt < 4; ++nt) {
    const ushort* brow = wT + (size_t)(n0 + nt * 16 + lo) * 64 + hi * 8;
    const bf16x8 b0 = *(const bf16x8*)(brow);
    const bf16x8 b1 = *(const bf16x8*)(brow + 32);
    f32x4 z = {0.f, 0.f, 0.f, 0.f};
    z = __builtin_amdgcn_mfma_f32_16x16x32_bf16(a0, b0, z, 0, 0, 0);
    z = __builtin_amdgcn_mfma_f32_16x16x32_bf16(a1, b1, z, 0, 0, 0);
    acc[nt] = z;
  }
  __shared__ ushort cs[64][72];  // 72: 16B-aligned row stride (144B)
#pragma unroll
  for (int nt = 0; nt < 4; ++nt) {
#pragma unroll
    for (int i = 0; i < 4; ++i) {
      const int rr = w * 16 + hi * 4 + i;
      const int cc = nt * 16 + lo;
      cs[rr][cc] = f2bf(acc[nt][i] + bias[n0 + cc]);
    }
  }
  __syncthreads();
  const int rr = t >> 2, c0 = (t & 3) * 16;
  const int gm = m0 + rr;
  if (gm < NN) {
    const uint4 v0 = *(const uint4*)&cs[rr][c0];
    const uint4 v1 = *(const uint4*)&cs[rr][c0 + 8];
    ushort* dst = qkv + (size_t)gm * 768 + n0 + c0;
    *(uint4*)(dst) = v0;
    *(uint4*)(dst + 8) = v1;
  }
}

// ---------------------------------------------------------------------------
// Attention: one wave per node; lane = (head h = l>>4) x (dgroup = l&15 -> 4 d).
// qkv row: [q(256) | k(256) | v(256)] bf16. Output attr[n][1024] at +r*256.
__global__ __launch_bounds__(256) void attn_kernel(
    const ushort* __restrict__ qkv, const int* __restrict__ offs,
    const int* __restrict__ csr, const float* __restrict__ nsi,
    const float* __restrict__ sw_lr, ushort* __restrict__ attr_r) {
  const int t = threadIdx.x;
  const int w = t >> 6, l = t & 63;
  const int n = blockIdx.x * 4 + w;
  if (n >= NN) return;
  const int h = l >> 4, dg = l & 15;
  const int off = h * 64 + dg * 4;
  const ushort4 qu = *(const ushort4*)(qkv + (size_t)n * 768 + off);
  const float q0 = bf2f(qu.x), q1 = bf2f(qu.y), q2 = bf2f(qu.z),
              q3 = bf2f(qu.w);
  const float c = 0.125f * nsi[n] * sw_lr[h * RR];
  const int s0 = offs[n], e0 = offs[n + 1];
  float m = -INFINITY, den = 0.f;
  float o0 = 0.f, o1 = 0.f, o2 = 0.f, o3 = 0.f;
  for (int i = s0; i < e0; ++i) {
    const int tg = csr[i];
    const ushort* kp = qkv + (size_t)tg * 768 + 256 + off;
    const ushort4 ku = *(const ushort4*)(kp);
    const ushort4 vu = *(const ushort4*)(kp + 256);
    float dot = q0 * bf2f(ku.x);
    dot = fmaf(q1, bf2f(ku.y), dot);
    dot = fmaf(q2, bf2f(ku.z), dot);
    dot = fmaf(q3, bf2f(ku.w), dot);
#pragma unroll
    for (int d = 1; d < 16; d <<= 1) dot += __shfl_xor(dot, d);
    const float s = dot * c;
    const float mn = fmaxf(m, s);
    const float esc = __expf(m - mn);
    const float ew = __expf(s - mn);
    den = den * esc + ew;
    o0 = fmaf(ew, bf2f(vu.x), o0 * esc);
    o1 = fmaf(ew, bf2f(vu.y), o1 * esc);
    o2 = fmaf(ew, bf2f(vu.z), o2 * esc);
    o3 = fmaf(ew, bf2f(vu.w), o3 * esc);
    m = mn;
  }
  const float inv = 1.f / (den + 1e-10f);
  ushort4 ou;
  ou.x = f2bf(o0 * inv);
  ou.y = f2bf(o1 * inv);
  ou.z = f2bf(o2 * inv);
  ou.w = f2bf(o3 * inv);
  *(ushort4*)(attr_r + (size_t)n * 1024 + off) = ou;
}

// ---------------------------------------------------------------------------
// Projection (K=1024) + bias + residual + LayerNorm, fused.
// grid (ceil(N/64)), block 256 = 4 waves; N-tile = 64 = full row.
__global__ __launch_bounds__(256) void proj_ln_kernel(
    const ushort* __restrict__ attr, const ushort* __restrict__ wpT,
    const float* __restrict__ xin, const float* __restrict__ bp,
    const float* __restrict__ g, const float* __restrict__ b,
    float* __restrict__ xout, ushort* __restrict__ xbf_out) {
  const int t = threadIdx.x;
  const int w = t >> 6, l = t & 63;
  const int hi = l >> 4, lo = l & 15;
  const int m0 = blockIdx.x * 64;
  const int arow_i = min(m0 + w * 16 + lo, NN - 1);
  const ushort* arow = attr + (size_t)arow_i * 1024 + hi * 8;
  f32x4 acc[4] = {{0.f, 0.f, 0.f, 0.f},
                  {0.f, 0.f, 0.f, 0.f},
                  {0.f, 0.f, 0.f, 0.f},
                  {0.f, 0.f, 0.f, 0.f}};
#pragma unroll 4
  for (int ks = 0; ks < 32; ++ks) {
    const bf16x8 a = *(const bf16x8*)(arow + ks * 32);
#pragma unroll
    for (int nt = 0; nt < 4; ++nt) {
      const bf16x8 bb =
          *(const bf16x8*)(wpT + (size_t)(nt * 16 + lo) * 1024 + ks * 32 + hi * 8);
      acc[nt] = __builtin_amdgcn_mfma_f32_16x16x32_bf16(a, bb, acc[nt], 0, 0, 0);
    }
  }
  // epilogue: y = x + attn_out + bp ; LN per row (16 lanes share a row)
#pragma unroll
  for (int i = 0; i < 4; ++i) {
    const int gr = m0 + w * 16 + hi * 4 + i;
    const int grc = min(gr, NN - 1);
    float y[4];
    float s = 0.f, s2 = 0.f;
#pragma unroll
    for (int nt = 0; nt < 4; ++nt) {
      const int col = nt * 16 + lo;
      const float yv = acc[nt][i] + bp[col] + xin[(size_t)grc * 64 + col];
      y[nt] = yv;
      s += yv;
      s2 = fmaf(yv, yv, s2);
    }
#pragma unroll
    for (int d = 1; d < 16; d <<= 1) {
      s += __shfl_xor(s, d);
      s2 += __shfl_xor(s2, d);
    }
    const float mu = s * (1.f / 64.f);
    const float var = s2 * (1.f / 64.f) - mu * mu;
    const float rstd = rsqrtf(var + 1e-5f);
    if (gr < NN) {
#pragma unroll
      for (int nt = 0; nt < 4; ++nt) {
        const int col = nt * 16 + lo;
        const float xo = (y[nt] - mu) * rstd * g[col] + b[col];
        xout[(size_t)gr * 64 + col] = xo;
        if (xbf_out) xbf_out[(size_t)gr * 64 + col] = f2bf(xo);
      }
    }
  }
}

// ---------------------------------------------------------------------------
extern "C" void kernel_launch(void* const* d_in, const int* in_sizes, int n_in,
                              void* d_out, int out_size, void* d_ws,
                              size_t ws_size, hipStream_t stream) {
  const float* feat = (const float*)d_in[1];
  const float* bet = (const float*)d_in[2];
  const float* clo = (const float*)d_in[3];
  const float* nsi = (const float*)d_in[4];
  const int* esrc = (const int*)d_in[5];
  const int* etgt = (const int*)d_in[6];
  const float* Wf = (const float*)d_in[7];
  const float* bf = (const float*)d_in[8];
  const float* Wc = (const float*)d_in[9];
  const float* bc = (const float*)d_in[10];
  const float* Wq = (const float*)d_in[11];
  const float* bq = (const float*)d_in[12];
  const float* Wk = (const float*)d_in[13];
  const float* bk = (const float*)d_in[14];
  const float* Wv = (const float*)d_in[15];
  const float* bv = (const float*)d_in[16];
  const float* Wp = (const float*)d_in[17];
  const float* bp = (const float*)d_in[18];
  const float* sw = (const float*)d_in[19];
  const float* lng = (const float*)d_in[20];
  const float* lnb = (const float*)d_in[21];
  float* out = (float*)d_out;

  char* base = (char*)d_ws;
  size_t off = 0;
  auto alloc = [&](size_t bytes) {
    void* p = base + off;
    off += (bytes + 255) & ~(size_t)255;
    return p;
  };
  float* xa = (float*)alloc((size_t)NN * DD * 4);          // 5.12 MB
  float* xb = (float*)alloc((size_t)NN * DD * 4);          // 5.12 MB
  ushort* xbf = (ushort*)alloc((size_t)NN * DD * 2);       // 2.56 MB
  ushort* qkv = (ushort*)alloc((size_t)NN * 768 * 2);      // 30.72 MB
  ushort* attr = (ushort*)alloc((size_t)NN * 1024 * 2);    // 40.96 MB
  ushort* wqkvT = (ushort*)alloc((size_t)LL * RR * 768 * 64 * 2);
  float* bqkv = (float*)alloc((size_t)LL * RR * 768 * 4);
  ushort* wpT = (ushort*)alloc((size_t)LL * 64 * 1024 * 2);
  int* counts = (int*)alloc((size_t)RR * NN * 4);
  int* offsb = (int*)alloc((size_t)RR * (NN + 1) * 4);
  int* bsum = (int*)alloc((size_t)RR * NB * 4);
  int* csr = (int*)alloc((size_t)RR * EE * 4);
  (void)ws_size;

  // ---- CSR build ----
  hipMemsetAsync(counts, 0, (size_t)RR * NN * 4, stream);
  {
    dim3 gg((EE + 255) / 256, RR);
    hipLaunchKernelGGL(hist_kernel, gg, dim3(256), 0, stream, esrc, counts);
  }
  {
    dim3 gg(NB, RR);
    hipLaunchKernelGGL(scanA_kernel, gg, dim3(256), 0, stream, counts, offsb,
                       bsum);
    hipLaunchKernelGGL(scanB_kernel, dim3(RR), dim3(128), 0, stream, bsum);
    hipLaunchKernelGGL(scanC_kernel, gg, dim3(256), 0, stream, bsum, offsb);
  }
  hipMemsetAsync(counts, 0, (size_t)RR * NN * 4, stream);  // reuse as cursor
  {
    dim3 gg((EE + 255) / 256, RR);
    hipLaunchKernelGGL(fill_kernel, gg, dim3(256), 0, stream, esrc, etgt, offsb,
                       counts, csr);
  }

  // ---- weight pre-pack + encoder ----
  hipLaunchKernelGGL(pack_kernel, dim3(2048), dim3(256), 0, stream, Wq, bq, Wk,
                     bk, Wv, bv, Wp, wqkvT, bqkv, wpT);
  hipLaunchKernelGGL(encoder_kernel, dim3((NN + 3) / 4), dim3(256), 0, stream,
                     feat, bet, clo, Wf, bf, Wc, bc, xa, xbf);

  const int gm = (NN + 63) / 64;  // 313
  for (int l = 0; l < LL; ++l) {
    const float* xin = (l == 0) ? xa : xb;
    float* xout = (l == LL - 1) ? out : xb;
    ushort* xbf_next = (l == LL - 1) ? (ushort*)nullptr : xbf;
    for (int r = 0; r < RR; ++r) {
      const int lr = l * RR + r;
      hipLaunchKernelGGL(qkv_gemm_kernel, dim3(gm, 12), dim3(256), 0, stream,
                         xbf, wqkvT + (size_t)lr * 49152, bqkv + lr * 768, qkv);
      hipLaunchKernelGGL(attn_kernel, dim3((NN + 3) / 4), dim3(256), 0, stream,
                         qkv, offsb + r * (NN + 1), csr + (size_t)r * EE, nsi,
                         sw + l * HH * RR + r, attr + r * 256);
    }
    hipLaunchKernelGGL(proj_ln_kernel, dim3(gm), dim3(256), 0, stream, attr,
                       wpT + (size_t)l * 65536, xin, bp + l * 64, lng + l * 64,
                       lnb + l * 64, xout, xbf_next);
  }
}

// Round 3
// 494.704 us; speedup vs baseline: 2.0998x; 1.1317x over previous
//
#include <hip/hip_runtime.h>
#include <math.h>

#define NN 20000
#define EE 100000
#define RR 4
#define HH 4
#define DD 64
#define FF 128
#define LL 2
#define NB 79  // scan blocks per relation: ceil(20000/256)

typedef __attribute__((ext_vector_type(8))) short bf16x8;
typedef __attribute__((ext_vector_type(4))) float f32x4;

__device__ __forceinline__ ushort f2bf(float f) {
  uint u = __float_as_uint(f);
  u += 0x7FFFu + ((u >> 16) & 1u);
  return (ushort)(u >> 16);
}
__device__ __forceinline__ float bf2f(ushort h) {
  return __uint_as_float((uint)h << 16);
}

// ---------------------------------------------------------------------------
// Encoder: x = feat@Wf + bf + cen@Wc + bc ; writes fp32 x and bf16 xbf
__global__ __launch_bounds__(256) void encoder_kernel(
    const float* __restrict__ feat, const float* __restrict__ bet,
    const float* __restrict__ clo, const float* __restrict__ Wf,
    const float* __restrict__ bf, const float* __restrict__ Wc,
    const float* __restrict__ bc, float* __restrict__ x,
    ushort* __restrict__ xbf) {
  __shared__ float fs[4][FF];
  const int t = threadIdx.x;
  const int n0 = blockIdx.x * 4;
  for (int idx = t; idx < 4 * FF; idx += 256) {
    const int rr = idx >> 7, cc = idx & 127;
    const int n = n0 + rr;
    fs[rr][cc] = (n < NN) ? feat[(size_t)n * FF + cc] : 0.f;
  }
  __syncthreads();
  const int g = t >> 6, d = t & 63;
  const int n = n0 + g;
  if (n >= NN) return;
  float acc = bf[d] + bc[d] + bet[n] * Wc[d] + clo[n] * Wc[DD + d];
#pragma unroll 8
  for (int f = 0; f < FF; ++f) acc = fmaf(fs[g][f], Wf[f * DD + d], acc);
  x[(size_t)n * DD + d] = acc;
  xbf[(size_t)n * DD + d] = f2bf(acc);
}

// ---------------------------------------------------------------------------
// Weight pre-pack: wqkvT [l][r][768][64] bf16 (B^T), bqkv [l][r][768] f32,
//                  wpT [l][64][1024] bf16 (B^T)
__global__ __launch_bounds__(256) void pack_kernel(
    const float* __restrict__ Wq, const float* __restrict__ bq,
    const float* __restrict__ Wk, const float* __restrict__ bk,
    const float* __restrict__ Wv, const float* __restrict__ bv,
    const float* __restrict__ Wp, ushort* __restrict__ wqkvT,
    float* __restrict__ bqkv, ushort* __restrict__ wpT) {
  const int idx = blockIdx.x * 256 + threadIdx.x;
  const int P1 = LL * RR * 768 * 64;  // 393216
  if (idx < P1) {
    const int lr = idx / 49152;
    const int rem = idx % 49152;
    const int n = rem >> 6, k = rem & 63;
    const int sel = n >> 8, col = n & 255;
    const float* W = (sel == 0) ? Wq : (sel == 1) ? Wk : Wv;
    wqkvT[(size_t)lr * 49152 + n * 64 + k] =
        f2bf(W[(size_t)lr * 64 * 256 + k * 256 + col]);
    if (k == 0) {
      const float* B = (sel == 0) ? bq : (sel == 1) ? bk : bv;
      bqkv[lr * 768 + n] = B[lr * 256 + col];
    }
  } else if (idx < P1 + LL * 64 * 1024) {
    const int idx2 = idx - P1;
    const int l = idx2 >> 16;
    const int rem = idx2 & 65535;
    const int n = rem & 63, k = rem >> 6;
    wpT[(size_t)l * 65536 + n * 1024 + k] =
        f2bf(Wp[(size_t)l * 65536 + k * 64 + n]);
  }
}

// ---------------------------------------------------------------------------
// CSR build
__global__ __launch_bounds__(256) void hist_kernel(
    const int* __restrict__ esrc, int* __restrict__ counts) {
  const int e = blockIdx.x * 256 + threadIdx.x;
  const int r = blockIdx.y;
  if (e < EE) atomicAdd(&counts[r * NN + esrc[(size_t)r * EE + e]], 1);
}

__global__ __launch_bounds__(256) void scanA_kernel(
    const int* __restrict__ counts, int* __restrict__ offs,
    int* __restrict__ bsum) {
  __shared__ int tmp[256];
  const int r = blockIdx.y, bx = blockIdx.x, t = threadIdx.x;
  const int i = bx * 256 + t;
  tmp[t] = (i < NN) ? counts[r * NN + i] : 0;
  __syncthreads();
#pragma unroll
  for (int s = 1; s < 256; s <<= 1) {
    const int add = (t >= s) ? tmp[t - s] : 0;
    __syncthreads();
    tmp[t] += add;
    __syncthreads();
  }
  if (i < NN) offs[r * (NN + 1) + i + 1] = tmp[t];
  if (t == 255) bsum[r * NB + bx] = tmp[255];
}

__global__ __launch_bounds__(128) void scanB_kernel(int* __restrict__ bsum) {
  __shared__ int tmp[128];
  const int r = blockIdx.x, t = threadIdx.x;
  tmp[t] = (t < NB) ? bsum[r * NB + t] : 0;
  __syncthreads();
#pragma unroll
  for (int s = 1; s < 128; s <<= 1) {
    const int add = (t >= s) ? tmp[t - s] : 0;
    __syncthreads();
    tmp[t] += add;
    __syncthreads();
  }
  if (t < NB) bsum[r * NB + t] = (t == 0) ? 0 : tmp[t - 1];
}

__global__ __launch_bounds__(256) void scanC_kernel(
    const int* __restrict__ bsum, int* __restrict__ offs) {
  const int r = blockIdx.y, bx = blockIdx.x, t = threadIdx.x;
  const int i = bx * 256 + t;
  if (i < NN) offs[r * (NN + 1) + i + 1] += bsum[r * NB + bx];
  if (i == 0) offs[r * (NN + 1)] = 0;
}

__global__ __launch_bounds__(256) void fill_kernel(
    const int* __restrict__ esrc, const int* __restrict__ etgt,
    const int* __restrict__ offs, int* __restrict__ cursor,
    int* __restrict__ csr) {
  const int e = blockIdx.x * 256 + threadIdx.x;
  const int r = blockIdx.y;
  if (e < EE) {
    const int s = esrc[(size_t)r * EE + e];
    const int pos = offs[r * (NN + 1) + s] + atomicAdd(&cursor[r * NN + s], 1);
    csr[(size_t)r * EE + pos] = etgt[(size_t)r * EE + e];
  }
}

// ---------------------------------------------------------------------------
// Fused Q|K|V GEMM: qkv[n][768] = xbf[n][64] @ wT^T + bias, bf16 out.
// grid (ceil(N/64), 12), block 256 = 4 waves; wave w: rows m0+w*16..+15.
__global__ __launch_bounds__(256) void qkv_gemm_kernel(
    const ushort* __restrict__ xbf, const ushort* __restrict__ wT,
    const float* __restrict__ bias, ushort* __restrict__ qkv) {
  const int t = threadIdx.x;
  const int w = t >> 6, l = t & 63;
  const int hi = l >> 4, lo = l & 15;
  const int m0 = blockIdx.x * 64;
  const int n0 = blockIdx.y * 64;
  const int row = min(m0 + w * 16 + lo, NN - 1);
  const ushort* arow = xbf + (size_t)row * 64 + hi * 8;
  const bf16x8 a0 = *(const bf16x8*)(arow);
  const bf16x8 a1 = *(const bf16x8*)(arow + 32);
  f32x4 acc[4];
#pragma unroll
  for (int nt = 0; nt < 4; ++nt) {
    const ushort* brow = wT + (size_t)(n0 + nt * 16 + lo) * 64 + hi * 8;
    const bf16x8 b0 = *(const bf16x8*)(brow);
    const bf16x8 b1 = *(const bf16x8*)(brow + 32);
    f32x4 z = {0.f, 0.f, 0.f, 0.f};
    z = __builtin_amdgcn_mfma_f32_16x16x32_bf16(a0, b0, z, 0, 0, 0);
    z = __builtin_amdgcn_mfma_f32_16x16x32_bf16(a1, b1, z, 0, 0, 0);
    acc[nt] = z;
  }
  __shared__ ushort cs[64][72];  // 72: 16B-aligned row stride (144B)
#pragma unroll
  for (int nt = 0; nt < 4; ++nt) {
#pragma unroll
    for (int i = 0; i < 4; ++i) {
      const int rr = w * 16 + hi * 4 + i;
      const int cc = nt * 16 + lo;
      cs[rr][cc] = f2bf(acc[nt][i] + bias[n0 + cc]);
    }
  }
  __syncthreads();
  const int rr = t >> 2, c0 = (t & 3) * 16;
  const int gm = m0 + rr;
  if (gm < NN) {
    const uint4 v0 = *(const uint4*)&cs[rr][c0];
    const uint4 v1 = *(const uint4*)&cs[rr][c0 + 8];
    ushort* dst = qkv + (size_t)gm * 768 + n0 + c0;
    *(uint4*)(dst) = v0;
    *(uint4*)(dst + 8) = v1;
  }
}

// ---------------------------------------------------------------------------
// Attention: one wave per node; lane l -> head h=l>>4, d-offset 4*l (mod 64).
// qkv row: [q(256) | k(256) | v(256)] bf16. Output attr[n][1024] at +r*256.
// Unroll-2: two independent online-softmax streams, merged at the end.
__global__ __launch_bounds__(256) void attn_kernel(
    const ushort* __restrict__ qkv, const int* __restrict__ offs,
    const int* __restrict__ csr, const float* __restrict__ nsi,
    const float* __restrict__ sw_lr, ushort* __restrict__ attr_r) {
  const int t = threadIdx.x;
  const int w = t >> 6, l = t & 63;
  const int n = blockIdx.x * 4 + w;
  if (n >= NN) return;
  const int h = l >> 4;
  const int off = l * 4;  // == h*64 + (l&15)*4
  const ushort4 qu = *(const ushort4*)(qkv + (size_t)n * 768 + off);
  const float q0 = bf2f(qu.x), q1 = bf2f(qu.y), q2 = bf2f(qu.z),
              q3 = bf2f(qu.w);
  const float c = 0.125f * nsi[n] * sw_lr[h * RR];
  const int s0 = offs[n], e0 = offs[n + 1];
  float mA = -INFINITY, dA = 0.f, oA0 = 0.f, oA1 = 0.f, oA2 = 0.f, oA3 = 0.f;
  float mB = -INFINITY, dB = 0.f, oB0 = 0.f, oB1 = 0.f, oB2 = 0.f, oB3 = 0.f;
  int i = s0;
  for (; i + 1 < e0; i += 2) {
    const int tgA = csr[i];
    const int tgB = csr[i + 1];
    const ushort* pA = qkv + (size_t)tgA * 768 + 256 + off;
    const ushort* pB = qkv + (size_t)tgB * 768 + 256 + off;
    const ushort4 kA = *(const ushort4*)(pA);
    const ushort4 kB = *(const ushort4*)(pB);
    const ushort4 vA = *(const ushort4*)(pA + 256);
    const ushort4 vB = *(const ushort4*)(pB + 256);
    float dotA = q0 * bf2f(kA.x);
    float dotB = q0 * bf2f(kB.x);
    dotA = fmaf(q1, bf2f(kA.y), dotA);
    dotB = fmaf(q1, bf2f(kB.y), dotB);
    dotA = fmaf(q2, bf2f(kA.z), dotA);
    dotB = fmaf(q2, bf2f(kB.z), dotB);
    dotA = fmaf(q3, bf2f(kA.w), dotA);
    dotB = fmaf(q3, bf2f(kB.w), dotB);
#pragma unroll
    for (int d = 1; d < 16; d <<= 1) {
      dotA += __shfl_xor(dotA, d);
      dotB += __shfl_xor(dotB, d);
    }
    const float sA = dotA * c;
    const float sB = dotB * c;
    const float mnA = fmaxf(mA, sA);
    const float mnB = fmaxf(mB, sB);
    const float escA = __expf(mA - mnA);
    const float escB = __expf(mB - mnB);
    const float ewA = __expf(sA - mnA);
    const float ewB = __expf(sB - mnB);
    dA = dA * escA + ewA;
    dB = dB * escB + ewB;
    oA0 = fmaf(ewA, bf2f(vA.x), oA0 * escA);
    oB0 = fmaf(ewB, bf2f(vB.x), oB0 * escB);
    oA1 = fmaf(ewA, bf2f(vA.y), oA1 * escA);
    oB1 = fmaf(ewB, bf2f(vB.y), oB1 * escB);
    oA2 = fmaf(ewA, bf2f(vA.z), oA2 * escA);
    oB2 = fmaf(ewB, bf2f(vB.z), oB2 * escB);
    oA3 = fmaf(ewA, bf2f(vA.w), oA3 * escA);
    oB3 = fmaf(ewB, bf2f(vB.w), oB3 * escB);
    mA = mnA;
    mB = mnB;
  }
  if (i < e0) {  // odd tail -> stream A
    const int tg = csr[i];
    const ushort* p = qkv + (size_t)tg * 768 + 256 + off;
    const ushort4 ku = *(const ushort4*)(p);
    const ushort4 vu = *(const ushort4*)(p + 256);
    float dot = q0 * bf2f(ku.x);
    dot = fmaf(q1, bf2f(ku.y), dot);
    dot = fmaf(q2, bf2f(ku.z), dot);
    dot = fmaf(q3, bf2f(ku.w), dot);
#pragma unroll
    for (int d = 1; d < 16; d <<= 1) dot += __shfl_xor(dot, d);
    const float s = dot * c;
    const float mn = fmaxf(mA, s);
    const float esc = __expf(mA - mn);
    const float ew = __expf(s - mn);
    dA = dA * esc + ew;
    oA0 = fmaf(ew, bf2f(vu.x), oA0 * esc);
    oA1 = fmaf(ew, bf2f(vu.y), oA1 * esc);
    oA2 = fmaf(ew, bf2f(vu.z), oA2 * esc);
    oA3 = fmaf(ew, bf2f(vu.w), oA3 * esc);
    mA = mn;
  }
  // merge streams (guard empty streams: exp(-inf - -inf) would be NaN)
  const float M = fmaxf(mA, mB);
  const float eA = (mA > -INFINITY) ? __expf(mA - M) : 0.f;
  const float eB = (mB > -INFINITY) ? __expf(mB - M) : 0.f;
  const float den = dA * eA + dB * eB;
  const float inv = 1.f / (den + 1e-10f);
  ushort4 ou;
  ou.x = f2bf((oA0 * eA + oB0 * eB) * inv);
  ou.y = f2bf((oA1 * eA + oB1 * eB) * inv);
  ou.z = f2bf((oA2 * eA + oB2 * eB) * inv);
  ou.w = f2bf((oA3 * eA + oB3 * eB) * inv);
  *(ushort4*)(attr_r + (size_t)n * 1024 + off) = ou;
}

// ---------------------------------------------------------------------------
// Projection (K=1024) + bias + residual + LayerNorm, fused.
// grid (N/16 = 1250), block 256 = 4 waves; each wave owns K-slice of 256;
// f32 partial reduce through LDS; wave 0 does the LN epilogue.
__global__ __launch_bounds__(256) void proj_ln_kernel(
    const ushort* __restrict__ attr, const ushort* __restrict__ wpT,
    const float* __restrict__ xin, const float* __restrict__ bp,
    const float* __restrict__ g, const float* __restrict__ b,
    float* __restrict__ xout, ushort* __restrict__ xbf_out) {
  __shared__ float red[4][64][20];  // [wave][lane][nt*4+i], pad to 80B stride
  const int t = threadIdx.x;
  const int w = t >> 6, l = t & 63;
  const int hi = l >> 4, lo = l & 15;
  const int m0 = blockIdx.x * 16;
  const ushort* arow = attr + (size_t)(m0 + lo) * 1024 + w * 256 + hi * 8;
  f32x4 acc[4] = {{0.f, 0.f, 0.f, 0.f},
                  {0.f, 0.f, 0.f, 0.f},
                  {0.f, 0.f, 0.f, 0.f},
                  {0.f, 0.f, 0.f, 0.f}};
#pragma unroll
  for (int ks = 0; ks < 8; ++ks) {
    const bf16x8 a = *(const bf16x8*)(arow + ks * 32);
#pragma unroll
    for (int nt = 0; nt < 4; ++nt) {
      const bf16x8 bb = *(const bf16x8*)(wpT + (size_t)(nt * 16 + lo) * 1024 +
                                         w * 256 + ks * 32 + hi * 8);
      acc[nt] = __builtin_amdgcn_mfma_f32_16x16x32_bf16(a, bb, acc[nt], 0, 0, 0);
    }
  }
#pragma unroll
  for (int nt = 0; nt < 4; ++nt) *(f32x4*)&red[w][l][nt * 4] = acc[nt];
  __syncthreads();
  if (w == 0) {
    f32x4 fin[4];
#pragma unroll
    for (int nt = 0; nt < 4; ++nt) {
      f32x4 s = *(const f32x4*)&red[0][l][nt * 4];
      s += *(const f32x4*)&red[1][l][nt * 4];
      s += *(const f32x4*)&red[2][l][nt * 4];
      s += *(const f32x4*)&red[3][l][nt * 4];
      fin[nt] = s;
    }
#pragma unroll
    for (int i = 0; i < 4; ++i) {
      const int gr = m0 + hi * 4 + i;
      float y[4];
      float s = 0.f, s2 = 0.f;
#pragma unroll
      for (int nt = 0; nt < 4; ++nt) {
        const int col = nt * 16 + lo;
        const float yv = fin[nt][i] + bp[col] + xin[(size_t)gr * 64 + col];
        y[nt] = yv;
        s += yv;
        s2 = fmaf(yv, yv, s2);
      }
#pragma unroll
      for (int d = 1; d < 16; d <<= 1) {
        s += __shfl_xor(s, d);
        s2 += __shfl_xor(s2, d);
      }
      const float mu = s * (1.f / 64.f);
      const float var = s2 * (1.f / 64.f) - mu * mu;
      const float rstd = rsqrtf(var + 1e-5f);
#pragma unroll
      for (int nt = 0; nt < 4; ++nt) {
        const int col = nt * 16 + lo;
        const float xo = (y[nt] - mu) * rstd * g[col] + b[col];
        xout[(size_t)gr * 64 + col] = xo;
        if (xbf_out) xbf_out[(size_t)gr * 64 + col] = f2bf(xo);
      }
    }
  }
}

// ---------------------------------------------------------------------------
extern "C" void kernel_launch(void* const* d_in, const int* in_sizes, int n_in,
                              void* d_out, int out_size, void* d_ws,
                              size_t ws_size, hipStream_t stream) {
  const float* feat = (const float*)d_in[1];
  const float* bet = (const float*)d_in[2];
  const float* clo = (const float*)d_in[3];
  const float* nsi = (const float*)d_in[4];
  const int* esrc = (const int*)d_in[5];
  const int* etgt = (const int*)d_in[6];
  const float* Wf = (const float*)d_in[7];
  const float* bf = (const float*)d_in[8];
  const float* Wc = (const float*)d_in[9];
  const float* bc = (const float*)d_in[10];
  const float* Wq = (const float*)d_in[11];
  const float* bq = (const float*)d_in[12];
  const float* Wk = (const float*)d_in[13];
  const float* bk = (const float*)d_in[14];
  const float* Wv = (const float*)d_in[15];
  const float* bv = (const float*)d_in[16];
  const float* Wp = (const float*)d_in[17];
  const float* bp = (const float*)d_in[18];
  const float* sw = (const float*)d_in[19];
  const float* lng = (const float*)d_in[20];
  const float* lnb = (const float*)d_in[21];
  float* out = (float*)d_out;

  char* base = (char*)d_ws;
  size_t off = 0;
  auto alloc = [&](size_t bytes) {
    void* p = base + off;
    off += (bytes + 255) & ~(size_t)255;
    return p;
  };
  float* xa = (float*)alloc((size_t)NN * DD * 4);          // 5.12 MB
  float* xb = (float*)alloc((size_t)NN * DD * 4);          // 5.12 MB
  ushort* xbf = (ushort*)alloc((size_t)NN * DD * 2);       // 2.56 MB
  ushort* qkv = (ushort*)alloc((size_t)NN * 768 * 2);      // 30.72 MB
  ushort* attr = (ushort*)alloc((size_t)NN * 1024 * 2);    // 40.96 MB
  ushort* wqkvT = (ushort*)alloc((size_t)LL * RR * 768 * 64 * 2);
  float* bqkv = (float*)alloc((size_t)LL * RR * 768 * 4);
  ushort* wpT = (ushort*)alloc((size_t)LL * 64 * 1024 * 2);
  int* counts = (int*)alloc((size_t)RR * NN * 4);
  int* offsb = (int*)alloc((size_t)RR * (NN + 1) * 4);
  int* bsum = (int*)alloc((size_t)RR * NB * 4);
  int* csr = (int*)alloc((size_t)RR * EE * 4);
  (void)ws_size;

  // ---- CSR build ----
  hipMemsetAsync(counts, 0, (size_t)RR * NN * 4, stream);
  {
    dim3 gg((EE + 255) / 256, RR);
    hipLaunchKernelGGL(hist_kernel, gg, dim3(256), 0, stream, esrc, counts);
  }
  {
    dim3 gg(NB, RR);
    hipLaunchKernelGGL(scanA_kernel, gg, dim3(256), 0, stream, counts, offsb,
                       bsum);
    hipLaunchKernelGGL(scanB_kernel, dim3(RR), dim3(128), 0, stream, bsum);
    hipLaunchKernelGGL(scanC_kernel, gg, dim3(256), 0, stream, bsum, offsb);
  }
  hipMemsetAsync(counts, 0, (size_t)RR * NN * 4, stream);  // reuse as cursor
  {
    dim3 gg((EE + 255) / 256, RR);
    hipLaunchKernelGGL(fill_kernel, gg, dim3(256), 0, stream, esrc, etgt, offsb,
                       counts, csr);
  }

  // ---- weight pre-pack + encoder ----
  hipLaunchKernelGGL(pack_kernel, dim3(2048), dim3(256), 0, stream, Wq, bq, Wk,
                     bk, Wv, bv, Wp, wqkvT, bqkv, wpT);
  hipLaunchKernelGGL(encoder_kernel, dim3((NN + 3) / 4), dim3(256), 0, stream,
                     feat, bet, clo, Wf, bf, Wc, bc, xa, xbf);

  const int gm = (NN + 63) / 64;  // 313
  for (int l = 0; l < LL; ++l) {
    const float* xin = (l == 0) ? xa : xb;
    float* xout = (l == LL - 1) ? out : xb;
    ushort* xbf_next = (l == LL - 1) ? (ushort*)nullptr : xbf;
    for (int r = 0; r < RR; ++r) {
      const int lr = l * RR + r;
      hipLaunchKernelGGL(qkv_gemm_kernel, dim3(gm, 12), dim3(256), 0, stream,
                         xbf, wqkvT + (size_t)lr * 49152, bqkv + lr * 768, qkv);
      hipLaunchKernelGGL(attn_kernel, dim3((NN + 3) / 4), dim3(256), 0, stream,
                         qkv, offsb + r * (NN + 1), csr + (size_t)r * EE, nsi,
                         sw + l * HH * RR + r, attr + r * 256);
    }
    hipLaunchKernelGGL(proj_ln_kernel, dim3(NN / 16), dim3(256), 0, stream,
                       attr, wpT + (size_t)l * 65536, xin, bp + l * 64,
                       lng + l * 64, lnb + l * 64, xout, xbf_next);
  }
}

// Round 4
// 421.583 us; speedup vs baseline: 2.4640x; 1.1734x over previous
//
#include <hip/hip_runtime.h>
#include <math.h>

#define NN 20000
#define EE 100000
#define RR 4
#define HH 4
#define DD 64
#define FF 128
#define LL 2
#define NB 79  // scan blocks per relation: ceil(20000/256)

typedef __attribute__((ext_vector_type(8))) short bf16x8;
typedef __attribute__((ext_vector_type(4))) float f32x4;

__device__ __forceinline__ ushort f2bf(float f) {
  uint u = __float_as_uint(f);
  u += 0x7FFFu + ((u >> 16) & 1u);
  return (ushort)(u >> 16);
}
__device__ __forceinline__ float bf2f(ushort h) {
  return __uint_as_float((uint)h << 16);
}

// ---------------------------------------------------------------------------
// Encoder: x = feat@Wf + bf + cen@Wc + bc ; writes fp32 x and bf16 xbf
__global__ __launch_bounds__(256) void encoder_kernel(
    const float* __restrict__ feat, const float* __restrict__ bet,
    const float* __restrict__ clo, const float* __restrict__ Wf,
    const float* __restrict__ bf, const float* __restrict__ Wc,
    const float* __restrict__ bc, float* __restrict__ x,
    ushort* __restrict__ xbf) {
  __shared__ float fs[4][FF];
  const int t = threadIdx.x;
  const int n0 = blockIdx.x * 4;
  for (int idx = t; idx < 4 * FF; idx += 256) {
    const int rr = idx >> 7, cc = idx & 127;
    const int n = n0 + rr;
    fs[rr][cc] = (n < NN) ? feat[(size_t)n * FF + cc] : 0.f;
  }
  __syncthreads();
  const int g = t >> 6, d = t & 63;
  const int n = n0 + g;
  if (n >= NN) return;
  float acc = bf[d] + bc[d] + bet[n] * Wc[d] + clo[n] * Wc[DD + d];
#pragma unroll 8
  for (int f = 0; f < FF; ++f) acc = fmaf(fs[g][f], Wf[f * DD + d], acc);
  x[(size_t)n * DD + d] = acc;
  xbf[(size_t)n * DD + d] = f2bf(acc);
}

// ---------------------------------------------------------------------------
// Weight pre-pack: wqkvT [l][r][768][64] bf16 (B^T), bqkv [l][r][768] f32,
//                  wpT [l][64][1024] bf16 (B^T)
__global__ __launch_bounds__(256) void pack_kernel(
    const float* __restrict__ Wq, const float* __restrict__ bq,
    const float* __restrict__ Wk, const float* __restrict__ bk,
    const float* __restrict__ Wv, const float* __restrict__ bv,
    const float* __restrict__ Wp, ushort* __restrict__ wqkvT,
    float* __restrict__ bqkv, ushort* __restrict__ wpT) {
  const int idx = blockIdx.x * 256 + threadIdx.x;
  const int P1 = LL * RR * 768 * 64;  // 393216
  if (idx < P1) {
    const int lr = idx / 49152;
    const int rem = idx % 49152;
    const int n = rem >> 6, k = rem & 63;
    const int sel = n >> 8, col = n & 255;
    const float* W = (sel == 0) ? Wq : (sel == 1) ? Wk : Wv;
    wqkvT[(size_t)lr * 49152 + n * 64 + k] =
        f2bf(W[(size_t)lr * 64 * 256 + k * 256 + col]);
    if (k == 0) {
      const float* B = (sel == 0) ? bq : (sel == 1) ? bk : bv;
      bqkv[lr * 768 + n] = B[lr * 256 + col];
    }
  } else if (idx < P1 + LL * 64 * 1024) {
    const int idx2 = idx - P1;
    const int l = idx2 >> 16;
    const int rem = idx2 & 65535;
    const int n = rem & 63, k = rem >> 6;
    wpT[(size_t)l * 65536 + n * 1024 + k] =
        f2bf(Wp[(size_t)l * 65536 + k * 64 + n]);
  }
}

// ---------------------------------------------------------------------------
// CSR build
__global__ __launch_bounds__(256) void hist_kernel(
    const int* __restrict__ esrc, int* __restrict__ counts) {
  const int e = blockIdx.x * 256 + threadIdx.x;
  const int r = blockIdx.y;
  if (e < EE) atomicAdd(&counts[r * NN + esrc[(size_t)r * EE + e]], 1);
}

__global__ __launch_bounds__(256) void scanA_kernel(
    const int* __restrict__ counts, int* __restrict__ offs,
    int* __restrict__ bsum) {
  __shared__ int tmp[256];
  const int r = blockIdx.y, bx = blockIdx.x, t = threadIdx.x;
  const int i = bx * 256 + t;
  tmp[t] = (i < NN) ? counts[r * NN + i] : 0;
  __syncthreads();
#pragma unroll
  for (int s = 1; s < 256; s <<= 1) {
    const int add = (t >= s) ? tmp[t - s] : 0;
    __syncthreads();
    tmp[t] += add;
    __syncthreads();
  }
  if (i < NN) offs[r * (NN + 1) + i + 1] = tmp[t];
  if (t == 255) bsum[r * NB + bx] = tmp[255];
}

__global__ __launch_bounds__(128) void scanB_kernel(int* __restrict__ bsum) {
  __shared__ int tmp[128];
  const int r = blockIdx.x, t = threadIdx.x;
  tmp[t] = (t < NB) ? bsum[r * NB + t] : 0;
  __syncthreads();
#pragma unroll
  for (int s = 1; s < 128; s <<= 1) {
    const int add = (t >= s) ? tmp[t - s] : 0;
    __syncthreads();
    tmp[t] += add;
    __syncthreads();
  }
  if (t < NB) bsum[r * NB + t] = (t == 0) ? 0 : tmp[t - 1];
}

__global__ __launch_bounds__(256) void scanC_kernel(
    const int* __restrict__ bsum, int* __restrict__ offs) {
  const int r = blockIdx.y, bx = blockIdx.x, t = threadIdx.x;
  const int i = bx * 256 + t;
  if (i < NN) offs[r * (NN + 1) + i + 1] += bsum[r * NB + bx];
  if (i == 0) offs[r * (NN + 1)] = 0;
}

__global__ __launch_bounds__(256) void fill_kernel(
    const int* __restrict__ esrc, const int* __restrict__ etgt,
    const int* __restrict__ offs, int* __restrict__ cursor,
    int* __restrict__ csr) {
  const int e = blockIdx.x * 256 + threadIdx.x;
  const int r = blockIdx.y;
  if (e < EE) {
    const int s = esrc[(size_t)r * EE + e];
    const int pos = offs[r * (NN + 1) + s] + atomicAdd(&cursor[r * NN + s], 1);
    csr[(size_t)r * EE + pos] = etgt[(size_t)r * EE + e];
  }
}

// ---------------------------------------------------------------------------
// Fused Q|K|V GEMM for ALL 4 relations of one layer.
// qkv4[n][r*768 + c] = xbf[n][64] @ wT[r]^T + bias[r], bf16 out.
// grid (ceil(N/64), 48): by -> r = by/12, n-tile = by%12. block 256 = 4 waves.
__global__ __launch_bounds__(256) void qkv_gemm_kernel(
    const ushort* __restrict__ xbf, const ushort* __restrict__ wqkvT_l,
    const float* __restrict__ bqkv_l, ushort* __restrict__ qkv4) {
  const int t = threadIdx.x;
  const int w = t >> 6, l = t & 63;
  const int hi = l >> 4, lo = l & 15;
  const int m0 = blockIdx.x * 64;
  const int r = blockIdx.y / 12;
  const int n0 = (blockIdx.y % 12) * 64;
  const ushort* wT = wqkvT_l + (size_t)r * 49152;
  const float* bias = bqkv_l + r * 768;
  const int row = min(m0 + w * 16 + lo, NN - 1);
  const ushort* arow = xbf + (size_t)row * 64 + hi * 8;
  const bf16x8 a0 = *(const bf16x8*)(arow);
  const bf16x8 a1 = *(const bf16x8*)(arow + 32);
  f32x4 acc[4];
#pragma unroll
  for (int nt = 0; nt < 4; ++nt) {
    const ushort* brow = wT + (size_t)(n0 + nt * 16 + lo) * 64 + hi * 8;
    const bf16x8 b0 = *(const bf16x8*)(brow);
    const bf16x8 b1 = *(const bf16x8*)(brow + 32);
    f32x4 z = {0.f, 0.f, 0.f, 0.f};
    z = __builtin_amdgcn_mfma_f32_16x16x32_bf16(a0, b0, z, 0, 0, 0);
    z = __builtin_amdgcn_mfma_f32_16x16x32_bf16(a1, b1, z, 0, 0, 0);
    acc[nt] = z;
  }
  __shared__ ushort cs[64][72];  // 72: 16B-aligned row stride (144B)
#pragma unroll
  for (int nt = 0; nt < 4; ++nt) {
#pragma unroll
    for (int i = 0; i < 4; ++i) {
      const int rr = w * 16 + hi * 4 + i;
      const int cc = nt * 16 + lo;
      cs[rr][cc] = f2bf(acc[nt][i] + bias[n0 + cc]);
    }
  }
  __syncthreads();
  const int rr = t >> 2, c0 = (t & 3) * 16;
  const int gm = m0 + rr;
  if (gm < NN) {
    const uint4 v0 = *(const uint4*)&cs[rr][c0];
    const uint4 v1 = *(const uint4*)&cs[rr][c0 + 8];
    ushort* dst = qkv4 + (size_t)gm * 3072 + r * 768 + n0 + c0;
    *(uint4*)(dst) = v0;
    *(uint4*)(dst + 8) = v1;
  }
}

// ---------------------------------------------------------------------------
// Attention, ALL relations in one dispatch: grid (ceil(N/4), 4), by = relation.
// One wave per node; lane l -> head h=l>>4, elem-offset 4*l (==h*64+(l&15)*4).
// qkv4 row for (n,r): [q(256) | k(256) | v(256)] bf16 at n*3072 + r*768.
// 4 independent online-softmax streams, merged at the end.
__global__ __launch_bounds__(256) void attn_kernel(
    const ushort* __restrict__ qkv4, const int* __restrict__ offs4,
    const int* __restrict__ csr4, const float* __restrict__ nsi,
    const float* __restrict__ sw_l, ushort* __restrict__ attr) {
  const int t = threadIdx.x;
  const int w = t >> 6, l = t & 63;
  const int n = blockIdx.x * 4 + w;
  if (n >= NN) return;
  const int r = blockIdx.y;
  const int* offs = offs4 + r * (NN + 1);
  const int* csr = csr4 + (size_t)r * EE;
  const int h = l >> 4;
  const int off = l * 4;
  const size_t rbase = (size_t)r * 768;
  const ushort4 qu = *(const ushort4*)(qkv4 + (size_t)n * 3072 + rbase + off);
  const float q0 = bf2f(qu.x), q1 = bf2f(qu.y), q2 = bf2f(qu.z),
              q3 = bf2f(qu.w);
  const float c = 0.125f * nsi[n] * sw_l[h * RR + r];
  const int s0 = offs[n], e0 = offs[n + 1];
  float m[4], den[4], o0[4], o1[4], o2[4], o3[4];
#pragma unroll
  for (int s = 0; s < 4; ++s) {
    m[s] = -INFINITY;
    den[s] = 0.f;
    o0[s] = 0.f;
    o1[s] = 0.f;
    o2[s] = 0.f;
    o3[s] = 0.f;
  }
  int i = s0;
  for (; i + 3 < e0; i += 4) {
    ushort4 ku[4], vu[4];
#pragma unroll
    for (int s = 0; s < 4; ++s) {
      const int tg = csr[i + s];
      const ushort* p = qkv4 + (size_t)tg * 3072 + rbase + 256 + off;
      ku[s] = *(const ushort4*)(p);
      vu[s] = *(const ushort4*)(p + 256);
    }
    float dot[4];
#pragma unroll
    for (int s = 0; s < 4; ++s) {
      float d = q0 * bf2f(ku[s].x);
      d = fmaf(q1, bf2f(ku[s].y), d);
      d = fmaf(q2, bf2f(ku[s].z), d);
      d = fmaf(q3, bf2f(ku[s].w), d);
      dot[s] = d;
    }
#pragma unroll
    for (int d = 1; d < 16; d <<= 1) {
#pragma unroll
      for (int s = 0; s < 4; ++s) dot[s] += __shfl_xor(dot[s], d);
    }
#pragma unroll
    for (int s = 0; s < 4; ++s) {
      const float sc = dot[s] * c;
      const float mn = fmaxf(m[s], sc);
      const float esc = __expf(m[s] - mn);
      const float ew = __expf(sc - mn);
      den[s] = den[s] * esc + ew;
      o0[s] = fmaf(ew, bf2f(vu[s].x), o0[s] * esc);
      o1[s] = fmaf(ew, bf2f(vu[s].y), o1[s] * esc);
      o2[s] = fmaf(ew, bf2f(vu[s].z), o2[s] * esc);
      o3[s] = fmaf(ew, bf2f(vu[s].w), o3[s] * esc);
      m[s] = mn;
    }
  }
  for (; i < e0; ++i) {  // tail -> stream 0
    const int tg = csr[i];
    const ushort* p = qkv4 + (size_t)tg * 3072 + rbase + 256 + off;
    const ushort4 ku = *(const ushort4*)(p);
    const ushort4 vu = *(const ushort4*)(p + 256);
    float d = q0 * bf2f(ku.x);
    d = fmaf(q1, bf2f(ku.y), d);
    d = fmaf(q2, bf2f(ku.z), d);
    d = fmaf(q3, bf2f(ku.w), d);
#pragma unroll
    for (int dd = 1; dd < 16; dd <<= 1) d += __shfl_xor(d, dd);
    const float sc = d * c;
    const float mn = fmaxf(m[0], sc);
    const float esc = __expf(m[0] - mn);
    const float ew = __expf(sc - mn);
    den[0] = den[0] * esc + ew;
    o0[0] = fmaf(ew, bf2f(vu.x), o0[0] * esc);
    o1[0] = fmaf(ew, bf2f(vu.y), o1[0] * esc);
    o2[0] = fmaf(ew, bf2f(vu.z), o2[0] * esc);
    o3[0] = fmaf(ew, bf2f(vu.w), o3[0] * esc);
    m[0] = mn;
  }
  // merge streams (guard empty streams: exp(-inf - -inf) would be NaN)
  float M = fmaxf(fmaxf(m[0], m[1]), fmaxf(m[2], m[3]));
  float D = 0.f, O0 = 0.f, O1 = 0.f, O2 = 0.f, O3 = 0.f;
#pragma unroll
  for (int s = 0; s < 4; ++s) {
    const float e = (m[s] > -INFINITY) ? __expf(m[s] - M) : 0.f;
    D = fmaf(den[s], e, D);
    O0 = fmaf(o0[s], e, O0);
    O1 = fmaf(o1[s], e, O1);
    O2 = fmaf(o2[s], e, O2);
    O3 = fmaf(o3[s], e, O3);
  }
  const float inv = 1.f / (D + 1e-10f);
  ushort4 ou;
  ou.x = f2bf(O0 * inv);
  ou.y = f2bf(O1 * inv);
  ou.z = f2bf(O2 * inv);
  ou.w = f2bf(O3 * inv);
  *(ushort4*)(attr + (size_t)n * 1024 + r * 256 + off) = ou;
}

// ---------------------------------------------------------------------------
// Projection (K=1024) + bias + residual + LayerNorm, fused.
// grid (N/16 = 1250), block 256 = 4 waves; each wave owns K-slice of 256;
// f32 partial reduce through LDS; wave 0 does the LN epilogue.
__global__ __launch_bounds__(256) void proj_ln_kernel(
    const ushort* __restrict__ attr, const ushort* __restrict__ wpT,
    const float* __restrict__ xin, const float* __restrict__ bp,
    const float* __restrict__ g, const float* __restrict__ b,
    float* __restrict__ xout, ushort* __restrict__ xbf_out) {
  __shared__ float red[4][64][20];  // [wave][lane][nt*4+i], pad to 80B stride
  const int t = threadIdx.x;
  const int w = t >> 6, l = t & 63;
  const int hi = l >> 4, lo = l & 15;
  const int m0 = blockIdx.x * 16;
  const ushort* arow = attr + (size_t)(m0 + lo) * 1024 + w * 256 + hi * 8;
  f32x4 acc[4] = {{0.f, 0.f, 0.f, 0.f},
                  {0.f, 0.f, 0.f, 0.f},
                  {0.f, 0.f, 0.f, 0.f},
                  {0.f, 0.f, 0.f, 0.f}};
#pragma unroll
  for (int ks = 0; ks < 8; ++ks) {
    const bf16x8 a = *(const bf16x8*)(arow + ks * 32);
#pragma unroll
    for (int nt = 0; nt < 4; ++nt) {
      const bf16x8 bb = *(const bf16x8*)(wpT + (size_t)(nt * 16 + lo) * 1024 +
                                         w * 256 + ks * 32 + hi * 8);
      acc[nt] = __builtin_amdgcn_mfma_f32_16x16x32_bf16(a, bb, acc[nt], 0, 0, 0);
    }
  }
#pragma unroll
  for (int nt = 0; nt < 4; ++nt) *(f32x4*)&red[w][l][nt * 4] = acc[nt];
  __syncthreads();
  if (w == 0) {
    f32x4 fin[4];
#pragma unroll
    for (int nt = 0; nt < 4; ++nt) {
      f32x4 s = *(const f32x4*)&red[0][l][nt * 4];
      s += *(const f32x4*)&red[1][l][nt * 4];
      s += *(const f32x4*)&red[2][l][nt * 4];
      s += *(const f32x4*)&red[3][l][nt * 4];
      fin[nt] = s;
    }
#pragma unroll
    for (int i = 0; i < 4; ++i) {
      const int gr = m0 + hi * 4 + i;
      float y[4];
      float s = 0.f, s2 = 0.f;
#pragma unroll
      for (int nt = 0; nt < 4; ++nt) {
        const int col = nt * 16 + lo;
        const float yv = fin[nt][i] + bp[col] + xin[(size_t)gr * 64 + col];
        y[nt] = yv;
        s += yv;
        s2 = fmaf(yv, yv, s2);
      }
#pragma unroll
      for (int d = 1; d < 16; d <<= 1) {
        s += __shfl_xor(s, d);
        s2 += __shfl_xor(s2, d);
      }
      const float mu = s * (1.f / 64.f);
      const float var = s2 * (1.f / 64.f) - mu * mu;
      const float rstd = rsqrtf(var + 1e-5f);
#pragma unroll
      for (int nt = 0; nt < 4; ++nt) {
        const int col = nt * 16 + lo;
        const float xo = (y[nt] - mu) * rstd * g[col] + b[col];
        xout[(size_t)gr * 64 + col] = xo;
        if (xbf_out) xbf_out[(size_t)gr * 64 + col] = f2bf(xo);
      }
    }
  }
}

// ---------------------------------------------------------------------------
extern "C" void kernel_launch(void* const* d_in, const int* in_sizes, int n_in,
                              void* d_out, int out_size, void* d_ws,
                              size_t ws_size, hipStream_t stream) {
  const float* feat = (const float*)d_in[1];
  const float* bet = (const float*)d_in[2];
  const float* clo = (const float*)d_in[3];
  const float* nsi = (const float*)d_in[4];
  const int* esrc = (const int*)d_in[5];
  const int* etgt = (const int*)d_in[6];
  const float* Wf = (const float*)d_in[7];
  const float* bf = (const float*)d_in[8];
  const float* Wc = (const float*)d_in[9];
  const float* bc = (const float*)d_in[10];
  const float* Wq = (const float*)d_in[11];
  const float* bq = (const float*)d_in[12];
  const float* Wk = (const float*)d_in[13];
  const float* bk = (const float*)d_in[14];
  const float* Wv = (const float*)d_in[15];
  const float* bv = (const float*)d_in[16];
  const float* Wp = (const float*)d_in[17];
  const float* bp = (const float*)d_in[18];
  const float* sw = (const float*)d_in[19];
  const float* lng = (const float*)d_in[20];
  const float* lnb = (const float*)d_in[21];
  float* out = (float*)d_out;

  char* base = (char*)d_ws;
  size_t off = 0;
  auto alloc = [&](size_t bytes) {
    void* p = base + off;
    off += (bytes + 255) & ~(size_t)255;
    return p;
  };
  float* xa = (float*)alloc((size_t)NN * DD * 4);           // 5.12 MB
  float* xb = (float*)alloc((size_t)NN * DD * 4);           // 5.12 MB
  ushort* xbf = (ushort*)alloc((size_t)NN * DD * 2);        // 2.56 MB
  ushort* qkv4 = (ushort*)alloc((size_t)NN * 3072 * 2);     // 122.88 MB
  ushort* attr = (ushort*)alloc((size_t)NN * 1024 * 2);     // 40.96 MB
  ushort* wqkvT = (ushort*)alloc((size_t)LL * RR * 768 * 64 * 2);
  float* bqkv = (float*)alloc((size_t)LL * RR * 768 * 4);
  ushort* wpT = (ushort*)alloc((size_t)LL * 64 * 1024 * 2);
  int* counts = (int*)alloc((size_t)RR * NN * 4);
  int* offsb = (int*)alloc((size_t)RR * (NN + 1) * 4);
  int* bsum = (int*)alloc((size_t)RR * NB * 4);
  int* csr = (int*)alloc((size_t)RR * EE * 4);
  (void)ws_size;

  // ---- CSR build ----
  hipMemsetAsync(counts, 0, (size_t)RR * NN * 4, stream);
  {
    dim3 gg((EE + 255) / 256, RR);
    hipLaunchKernelGGL(hist_kernel, gg, dim3(256), 0, stream, esrc, counts);
  }
  {
    dim3 gg(NB, RR);
    hipLaunchKernelGGL(scanA_kernel, gg, dim3(256), 0, stream, counts, offsb,
                       bsum);
    hipLaunchKernelGGL(scanB_kernel, dim3(RR), dim3(128), 0, stream, bsum);
    hipLaunchKernelGGL(scanC_kernel, gg, dim3(256), 0, stream, bsum, offsb);
  }
  hipMemsetAsync(counts, 0, (size_t)RR * NN * 4, stream);  // reuse as cursor
  {
    dim3 gg((EE + 255) / 256, RR);
    hipLaunchKernelGGL(fill_kernel, gg, dim3(256), 0, stream, esrc, etgt, offsb,
                       counts, csr);
  }

  // ---- weight pre-pack + encoder ----
  hipLaunchKernelGGL(pack_kernel, dim3(2048), dim3(256), 0, stream, Wq, bq, Wk,
                     bk, Wv, bv, Wp, wqkvT, bqkv, wpT);
  hipLaunchKernelGGL(encoder_kernel, dim3((NN + 3) / 4), dim3(256), 0, stream,
                     feat, bet, clo, Wf, bf, Wc, bc, xa, xbf);

  const int gm = (NN + 63) / 64;  // 313
  for (int l = 0; l < LL; ++l) {
    const float* xin = (l == 0) ? xa : xb;
    float* xout = (l == LL - 1) ? out : xb;
    ushort* xbf_next = (l == LL - 1) ? (ushort*)nullptr : xbf;
    hipLaunchKernelGGL(qkv_gemm_kernel, dim3(gm, 48), dim3(256), 0, stream, xbf,
                       wqkvT + (size_t)l * RR * 49152, bqkv + l * RR * 768,
                       qkv4);
    hipLaunchKernelGGL(attn_kernel, dim3((NN + 3) / 4, RR), dim3(256), 0,
                       stream, qkv4, offsb, csr, nsi, sw + l * HH * RR, attr);
    hipLaunchKernelGGL(proj_ln_kernel, dim3(NN / 16), dim3(256), 0, stream,
                       attr, wpT + (size_t)l * 65536, xin, bp + l * 64,
                       lng + l * 64, lnb + l * 64, xout, xbf_next);
  }
}